// Round 10
// baseline (515.026 us; speedup 1.0000x reference)
//
#include <hip/hip_runtime.h>

#define NN 50000
#define NE 800000
#define HID 128
#define OUTD 64
#define NB 1563   // ceil(NN/32) buckets for two-level scatter

typedef __attribute__((ext_vector_type(8))) short bf16x8;
typedef __attribute__((ext_vector_type(4))) float f32x4;

static __device__ __forceinline__ unsigned short f2bf(float f) {
    unsigned u = __float_as_uint(f);
    unsigned r = (u + 0x7FFFu + ((u >> 16) & 1u)) >> 16;   // RNE
    return (unsigned short)r;
}
static __device__ __forceinline__ float bflo(unsigned u) { return __uint_as_float(u << 16); }
static __device__ __forceinline__ float bfhi(unsigned u) { return __uint_as_float(u & 0xffff0000u); }

// ---------------- CSR build: fused per-dst + per-bucket histogram ----------------
__global__ void histB_kernel(const int* __restrict__ dst, int* __restrict__ cnt,
                             int* __restrict__ cntB) {
    int e = blockIdx.x * blockDim.x + threadIdx.x;
    if (e < NE) {
        int d = dst[e];
        atomicAdd(&cnt[d], 1);
        atomicAdd(&cntB[d >> 5], 1);
    }
}

// ---------------- 3-phase exclusive scan over NN counts ----------------
__global__ void scan1_kernel(const int* __restrict__ cnt, int* __restrict__ excl,
                             int* __restrict__ bsum) {
    __shared__ int tmp[256];
    int tid = threadIdx.x;
    int i = blockIdx.x * 256 + tid;
    int v = (i < NN) ? cnt[i] : 0;
    tmp[tid] = v;
    __syncthreads();
    for (int off = 1; off < 256; off <<= 1) {
        int t = (tid >= off) ? tmp[tid - off] : 0;
        __syncthreads();
        tmp[tid] += t;
        __syncthreads();
    }
    if (i < NN) excl[i] = tmp[tid] - v;
    if (tid == 255) bsum[blockIdx.x] = tmp[255];
}

__global__ void scan2_kernel(int* __restrict__ bsum, int* __restrict__ boff, int nb) {
    __shared__ int tmp[256];
    int tid = threadIdx.x;
    int v = (tid < nb) ? bsum[tid] : 0;
    tmp[tid] = v;
    __syncthreads();
    for (int off = 1; off < 256; off <<= 1) {
        int t = (tid >= off) ? tmp[tid - off] : 0;
        __syncthreads();
        tmp[tid] += t;
        __syncthreads();
    }
    if (tid < nb) boff[tid] = tmp[tid] - v;
}

__global__ void scan3_kernel(int* __restrict__ excl, const int* __restrict__ boff,
                             int* __restrict__ next) {
    int i = blockIdx.x * 256 + threadIdx.x;
    if (i < NN) {
        int s = excl[i] + boff[blockIdx.x];
        excl[i] = s;
        next[i] = s;
    }
}

// ---------------- single-block scan over NB bucket counts -> bstart/bcur ----------------
__global__ void scanB_kernel(const int* __restrict__ cntB, int* __restrict__ bcur) {
    __shared__ int tmp[256];
    __shared__ int carry;
    int tid = threadIdx.x;
    if (tid == 0) carry = 0;
    __syncthreads();
    for (int base = 0; base < NB; base += 256) {
        int i = base + tid;
        int v = (i < NB) ? cntB[i] : 0;
        tmp[tid] = v;
        __syncthreads();
        for (int off = 1; off < 256; off <<= 1) {
            int t = (tid >= off) ? tmp[tid - off] : 0;
            __syncthreads();
            tmp[tid] += t;
            __syncthreads();
        }
        if (i < NB) bcur[i] = tmp[tid] - v + carry;
        __syncthreads();
        if (tid == 255) carry += tmp[255];
        __syncthreads();
    }
}

// ---------------- pass A: scatter (src,dst) pairs into bucket order ----------------
__global__ void pairscat_kernel(const int* __restrict__ src, const int* __restrict__ dst,
                                int* __restrict__ bcur, int2* __restrict__ pairs) {
    int e = blockIdx.x * blockDim.x + threadIdx.x;
    if (e < NE) {
        int s = src[e], d = dst[e];
        int pos = atomicAdd(&bcur[d >> 5], 1);
        pairs[pos] = make_int2(s, d);
    }
}

// ---------------- pass B: bucket-ordered pairs -> CSR perm (localized writes) --------
__global__ void finalscat_kernel(const int2* __restrict__ pairs, int* __restrict__ next,
                                 int* __restrict__ perm) {
    int i = blockIdx.x * blockDim.x + threadIdx.x;
    if (i < NE) {
        int2 p = pairs[i];
        int pos = atomicAdd(&next[p.y], 1);
        perm[pos] = p.x;
    }
}

// ---------------- weight prep: BT1[j][k], BT2[j][k] bf16 (transposed, k-contig) --------
__global__ void wprep_kernel(const float* __restrict__ W1l, const float* __restrict__ W1r,
                             const float* __restrict__ W2l, const float* __restrict__ W2r,
                             unsigned short* __restrict__ BT1, unsigned short* __restrict__ BT2) {
    int idx = blockIdx.x * 256 + threadIdx.x;
    if (idx >= 128 * 128) return;
    int j = idx >> 7, k = idx & 127;
    float v1 = (k < 64) ? W1l[k * HID + j] : W1r[(k - 64) * HID + j];
    BT1[j * 128 + k] = f2bf(v1);
    float v2 = (j < 64) ? W2l[k * OUTD + j] : W2r[k * OUTD + (j - 64)];
    BT2[j * 128 + k] = f2bf(v2);
}

// ---------------- x -> bf16 into A1 cols [64:128) ----------------
__global__ void x2bf_kernel(const float* __restrict__ x, unsigned short* __restrict__ A1) {
    int idx = blockIdx.x * 256 + threadIdx.x;   // NN*16 float4 slots
    if (idx >= NN * 16) return;
    int n = idx >> 4, q = idx & 15;
    float4 v = ((const float4*)x)[idx];
    ushort4 o;
    o.x = f2bf(v.x); o.y = f2bf(v.y); o.z = f2bf(v.z); o.w = f2bf(v.w);
    *(ushort4*)(A1 + (size_t)n * 128 + 64 + q * 4) = o;
}

// ---------------- gather-aggregate over bf16 rows, one wave per node --------
// MODE 0: store bf16 mean into outb row; MODE 1: outf[n*64+c] += mean (fp32)
template<int MODE>
__global__ __launch_bounds__(256) void agg_gather_b(
    const unsigned short* __restrict__ feat, int fstride, int foff,
    const int* __restrict__ start, const int* __restrict__ perm,
    unsigned short* __restrict__ outb, int ostride, int ooff,
    float* __restrict__ outf)
{
    int wave = (blockIdx.x * blockDim.x + threadIdx.x) >> 6;
    if (wave >= NN) return;
    int lane = threadIdx.x & 63;
    int g = lane >> 3;        // 8 edge groups
    int q = lane & 7;         // 8 bf16 per slot
    int rs = start[wave];
    int re = (wave == NN - 1) ? NE : start[wave + 1];
    float acc[8];
#pragma unroll
    for (int t = 0; t < 8; t++) acc[t] = 0.f;
    for (int i = rs + g; i < re; i += 8) {
        int s = perm[i];
        uint4 v = *(const uint4*)(feat + (size_t)s * fstride + foff + q * 8);
        acc[0] += bflo(v.x); acc[1] += bfhi(v.x);
        acc[2] += bflo(v.y); acc[3] += bfhi(v.y);
        acc[4] += bflo(v.z); acc[5] += bfhi(v.z);
        acc[6] += bflo(v.w); acc[7] += bfhi(v.w);
    }
#pragma unroll
    for (int t = 0; t < 8; t++) {
        acc[t] += __shfl_xor(acc[t], 8, 64);
        acc[t] += __shfl_xor(acc[t], 16, 64);
        acc[t] += __shfl_xor(acc[t], 32, 64);
    }
    if (g == 0) {
        int cnt = re - rs;
        float inv = (cnt > 0) ? (1.0f / (float)cnt) : 0.f;
        if (MODE == 0) {
            uint4 o;
            o.x = (unsigned)f2bf(acc[0] * inv) | ((unsigned)f2bf(acc[1] * inv) << 16);
            o.y = (unsigned)f2bf(acc[2] * inv) | ((unsigned)f2bf(acc[3] * inv) << 16);
            o.z = (unsigned)f2bf(acc[4] * inv) | ((unsigned)f2bf(acc[5] * inv) << 16);
            o.w = (unsigned)f2bf(acc[6] * inv) | ((unsigned)f2bf(acc[7] * inv) << 16);
            *(uint4*)(outb + (size_t)wave * ostride + ooff + q * 8) = o;
        } else {
            float4* op = (float4*)(outf + (size_t)wave * 64 + q * 8);
            float4 o0 = op[0], o1 = op[1];
            o0.x += acc[0] * inv; o0.y += acc[1] * inv;
            o0.z += acc[2] * inv; o0.w += acc[3] * inv;
            o1.x += acc[4] * inv; o1.y += acc[5] * inv;
            o1.z += acc[6] * inv; o1.w += acc[7] * inv;
            op[0] = o0; op[1] = o1;
        }
    }
}

// ---------------- MFMA conv: B in registers, multi-tile per wave, A prefetch -------
template<bool IS1>
__global__ __launch_bounds__(256) void conv_mfma_kernel(
    const unsigned short* __restrict__ A, const unsigned short* __restrict__ BT,
    const float* __restrict__ bias,
    unsigned short* __restrict__ outb, float* __restrict__ outf,
    float* __restrict__ sums, float* __restrict__ sumsq)
{
    __shared__ float red_s[4][128];
    __shared__ float red_q[4][128];
    int tid = threadIdx.x;
    int wid = tid >> 6, lane = tid & 63;
    int m = lane & 15, ko = lane >> 4;
    int gw = blockIdx.x * 4 + wid;
    int jh = gw & 1;                       // j-half this wave owns
    int tstride = (gridDim.x * 4) >> 1;
    const int tiles = NN / 16;             // 3125, exact
    // preload B fragments for this j-half (16 x bf16x8 = 64 VGPRs)
    bf16x8 b[4][4];
    const unsigned short* bbase = BT + (size_t)(jh * 64 + m) * 128 + ko * 8;
#pragma unroll
    for (int jg = 0; jg < 4; jg++)
#pragma unroll
        for (int ks = 0; ks < 4; ks++)
            b[jg][ks] = *(const bf16x8*)(bbase + jg * 16 * 128 + ks * 32);
    float bj[4];
#pragma unroll
    for (int jg = 0; jg < 4; jg++)
        bj[jg] = IS1 ? bias[jh * 64 + jg * 16 + m] : (jh ? bias[jg * 16 + m] : 0.f);
    float s_sum[4] = {0.f, 0.f, 0.f, 0.f}, s_sq[4] = {0.f, 0.f, 0.f, 0.f};
    int tile = gw >> 1;
    bf16x8 a[4];
    if (tile < tiles) {
        const unsigned short* arow = A + (size_t)(tile * 16 + m) * 128 + ko * 8;
#pragma unroll
        for (int ks = 0; ks < 4; ks++) a[ks] = *(const bf16x8*)(arow + ks * 32);
    }
    while (tile < tiles) {
        int nxt = tile + tstride;
        bf16x8 an[4];
        if (nxt < tiles) {
            const unsigned short* arow = A + (size_t)(nxt * 16 + m) * 128 + ko * 8;
#pragma unroll
            for (int ks = 0; ks < 4; ks++) an[ks] = *(const bf16x8*)(arow + ks * 32);
        }
        int n0 = tile * 16;
#pragma unroll
        for (int jg = 0; jg < 4; jg++) {
            f32x4 acc = {0.f, 0.f, 0.f, 0.f};
#pragma unroll
            for (int ks = 0; ks < 4; ks++)
                acc = __builtin_amdgcn_mfma_f32_16x16x32_bf16(a[ks], b[jg][ks], acc, 0, 0, 0);
            int j = jh * 64 + jg * 16 + m;
#pragma unroll
            for (int r = 0; r < 4; r++) {
                int n = n0 + ko * 4 + r;
                float v = acc[r];
                if (IS1) {
                    v += bj[jg];
                    outb[(size_t)n * 128 + j] = f2bf(v);
                    s_sum[jg] += v;
                    s_sq[jg] += v * v;
                } else {
                    if (jh == 0) outb[(size_t)n * 64 + j] = f2bf(v);
                    else         outf[(size_t)n * 64 + (j - 64)] = v + bj[jg];
                }
            }
        }
#pragma unroll
        for (int ks = 0; ks < 4; ks++) a[ks] = an[ks];
        tile = nxt;
    }
    if (IS1) {
        for (int i = tid; i < 512; i += 256) {
            ((float*)red_s)[i] = 0.f;
            ((float*)red_q)[i] = 0.f;
        }
        __syncthreads();
#pragma unroll
        for (int jg = 0; jg < 4; jg++) {
            float v = s_sum[jg];
            v += __shfl_xor(v, 16, 64);
            v += __shfl_xor(v, 32, 64);
            float w = s_sq[jg];
            w += __shfl_xor(w, 16, 64);
            w += __shfl_xor(w, 32, 64);
            if (lane < 16) {
                red_s[wid][jh * 64 + jg * 16 + lane] = v;
                red_q[wid][jh * 64 + jg * 16 + lane] = w;
            }
        }
        __syncthreads();
        if (tid < 128) {
            float v = red_s[0][tid] + red_s[1][tid] + red_s[2][tid] + red_s[3][tid];
            atomicAdd(&sums[tid], v);
        } else {
            int j = tid - 128;
            float v = red_q[0][j] + red_q[1][j] + red_q[2][j] + red_q[3][j];
            atomicAdd(&sumsq[j], v);
        }
    }
}

// ---------------- BN stats -> scale/shift ----------------
__global__ void bnstat_kernel(const float* __restrict__ sums, const float* __restrict__ sumsq,
                              const float* __restrict__ gamma, const float* __restrict__ beta,
                              float* __restrict__ scale, float* __restrict__ shift) {
    int c = threadIdx.x;
    if (c < HID) {
        float inv_n = 1.0f / (float)NN;
        float mu = sums[c] * inv_n;
        float var = sumsq[c] * inv_n - mu * mu;
        float s = gamma[c] * rsqrtf(var + 1e-5f);
        scale[c] = s;
        shift[c] = beta[c] - mu * s;
    }
}

// ---------------- bn+relu apply: h = relu(bn(hpreb)) bf16 -> A1 ----------------
__global__ void bnapply_kernel(const unsigned short* __restrict__ hpreb,
                               const float* __restrict__ scale, const float* __restrict__ shift,
                               unsigned short* __restrict__ A1) {
    int idx = blockIdx.x * 256 + threadIdx.x;   // NN*16 octet slots
    if (idx >= NN * 16) return;
    int q = idx & 15;
    int j0 = q * 8;
    uint4 v = ((const uint4*)hpreb)[idx];
    float f[8];
    f[0] = bflo(v.x); f[1] = bfhi(v.x);
    f[2] = bflo(v.y); f[3] = bfhi(v.y);
    f[4] = bflo(v.z); f[5] = bfhi(v.z);
    f[6] = bflo(v.w); f[7] = bfhi(v.w);
#pragma unroll
    for (int t = 0; t < 8; t++) {
        float h = f[t] * scale[j0 + t] + shift[j0 + t];
        f[t] = h > 0.f ? h : 0.f;
    }
    uint4 o;
    o.x = (unsigned)f2bf(f[0]) | ((unsigned)f2bf(f[1]) << 16);
    o.y = (unsigned)f2bf(f[2]) | ((unsigned)f2bf(f[3]) << 16);
    o.z = (unsigned)f2bf(f[4]) | ((unsigned)f2bf(f[5]) << 16);
    o.w = (unsigned)f2bf(f[6]) | ((unsigned)f2bf(f[7]) << 16);
    ((uint4*)A1)[idx] = o;
}

extern "C" void kernel_launch(void* const* d_in, const int* in_sizes, int n_in,
                              void* d_out, int out_size, void* d_ws, size_t ws_size,
                              hipStream_t stream) {
    const float* x     = (const float*)d_in[0];
    const int*   ei    = (const int*)d_in[1];
    const float* W1l   = (const float*)d_in[2];
    const float* b1    = (const float*)d_in[3];
    const float* W1r   = (const float*)d_in[4];
    const float* gamma = (const float*)d_in[5];
    const float* beta  = (const float*)d_in[6];
    const float* W2l   = (const float*)d_in[7];
    const float* b2    = (const float*)d_in[8];
    const float* W2r   = (const float*)d_in[9];
    float* out = (float*)d_out;

    // workspace layout (~35.7 MB; proven-safe bound is >= 38.6 MB)
    char* wsb = (char*)d_ws;
    int*   cnt    = (int*)wsb;                                  // NN   (reused as CSR cursor)
    int*   cntB   = cnt + NN;                                   // NB   (adjacent: one memset)
    int*   startp = cntB + NB;                                  // NN
    int*   bsum   = startp + NN;                                // 256
    int*   boff   = bsum + 256;                                 // 256
    int*   bcur   = boff + 256;                                 // NB
    int*   perm   = bcur + NB;                                  // NE
    int2*  pairs  = (int2*)(perm + NE);                         // NE int2 (6.4 MB)
    unsigned short* A1    = (unsigned short*)(pairs + NE);      // NN*128 bf16
    unsigned short* hpreb = A1 + (size_t)NN * 128;              // NN*128 bf16; reused as pb
    unsigned short* BT1   = hpreb + (size_t)NN * 128;           // 128*128 bf16
    unsigned short* BT2   = BT1 + 128 * 128;                    // 128*128 bf16
    float* sums  = (float*)(BT2 + 128 * 128);                   // 128
    float* sumsq = sums + 128;                                  // 128
    float* scale = sums + 256;                                  // 128
    float* shift = sums + 384;                                  // 128

    const int* srcp = ei;
    const int* dstp = ei + NE;

    hipMemsetAsync(cnt, 0, sizeof(int) * (NN + NB), stream);
    hipMemsetAsync(sums, 0, sizeof(float) * 256, stream);

    const int EB = (NE + 255) / 256;
    const int SB = (NN + 255) / 256;
    const int GB = (NN * 64 + 255) / 256;   // one wave per node
    const int XB = (NN * 16 + 255) / 256;
    const int CB = 512;                     // 2048 waves, ~3 tiles each

    histB_kernel<<<EB, 256, 0, stream>>>(dstp, cnt, cntB);
    scan1_kernel<<<SB, 256, 0, stream>>>(cnt, startp, bsum);
    scan2_kernel<<<1, 256, 0, stream>>>(bsum, boff, SB);
    scan3_kernel<<<SB, 256, 0, stream>>>(startp, boff, cnt);   // cnt becomes CSR cursor
    scanB_kernel<<<1, 256, 0, stream>>>(cntB, bcur);
    pairscat_kernel<<<EB, 256, 0, stream>>>(srcp, dstp, bcur, pairs);
    finalscat_kernel<<<EB, 256, 0, stream>>>(pairs, cnt, perm);

    wprep_kernel<<<64, 256, 0, stream>>>(W1l, W1r, W2l, W2r, BT1, BT2);
    x2bf_kernel<<<XB, 256, 0, stream>>>(x, A1);

    // agg1: gather A1 x-half (cols 64:128) -> bf16 mean into A1 cols 0:64
    agg_gather_b<0><<<GB, 256, 0, stream>>>(A1, 128, 64, startp, perm, A1, 128, 0, nullptr);
    // conv1: hpre = A1 @ [W1l;W1r] + b1 ; bf16 store + fp32 BN stats
    conv_mfma_kernel<true><<<CB, 256, 0, stream>>>(A1, BT1, b1, hpreb, nullptr, sums, sumsq);
    bnstat_kernel<<<1, 128, 0, stream>>>(sums, sumsq, gamma, beta, scale, shift);
    // h = relu(bn(hpreb)) -> A1
    bnapply_kernel<<<XB, 256, 0, stream>>>(hpreb, scale, shift, A1);
    // conv2: [p | self] = A1 @ [W2l|W2r] ; p bf16 -> hpreb(=pb), self+b2 -> out
    conv_mfma_kernel<false><<<CB, 256, 0, stream>>>(A1, BT2, b2, hpreb, out, nullptr, nullptr);
    // agg2: gather pb rows -> out += mean
    agg_gather_b<1><<<GB, 256, 0, stream>>>(hpreb, 64, 0, startp, perm, nullptr, 0, 0, out);
}

// Round 11
// 272.384 us; speedup vs baseline: 1.8908x; 1.8908x over previous
//
#include <hip/hip_runtime.h>

#define NN 50000
#define NE 800000
#define HID 128
#define OUTD 64

typedef __attribute__((ext_vector_type(8))) short bf16x8;
typedef __attribute__((ext_vector_type(4))) float f32x4;

static __device__ __forceinline__ unsigned short f2bf(float f) {
    unsigned u = __float_as_uint(f);
    unsigned r = (u + 0x7FFFu + ((u >> 16) & 1u)) >> 16;   // RNE
    return (unsigned short)r;
}
static __device__ __forceinline__ float bflo(unsigned u) { return __uint_as_float(u << 16); }
static __device__ __forceinline__ float bfhi(unsigned u) { return __uint_as_float(u & 0xffff0000u); }

// ---------------- CSR build ----------------
__global__ void hist_kernel(const int* __restrict__ dst, int* __restrict__ cnt) {
    int e = blockIdx.x * blockDim.x + threadIdx.x;
    if (e < NE) {
        int d = __builtin_nontemporal_load(&dst[e]);   // don't pollute L2
        atomicAdd(&cnt[d], 1);
    }
}

__global__ void scan1_kernel(const int* __restrict__ cnt, int* __restrict__ excl,
                             int* __restrict__ bsum) {
    __shared__ int tmp[256];
    int tid = threadIdx.x;
    int i = blockIdx.x * 256 + tid;
    int v = (i < NN) ? cnt[i] : 0;
    tmp[tid] = v;
    __syncthreads();
    for (int off = 1; off < 256; off <<= 1) {
        int t = (tid >= off) ? tmp[tid - off] : 0;
        __syncthreads();
        tmp[tid] += t;
        __syncthreads();
    }
    if (i < NN) excl[i] = tmp[tid] - v;
    if (tid == 255) bsum[blockIdx.x] = tmp[255];
}

__global__ void scan2_kernel(int* __restrict__ bsum, int* __restrict__ boff, int nb) {
    __shared__ int tmp[256];
    int tid = threadIdx.x;
    int v = (tid < nb) ? bsum[tid] : 0;
    tmp[tid] = v;
    __syncthreads();
    for (int off = 1; off < 256; off <<= 1) {
        int t = (tid >= off) ? tmp[tid - off] : 0;
        __syncthreads();
        tmp[tid] += t;
        __syncthreads();
    }
    if (tid < nb) boff[tid] = tmp[tid] - v;
}

__global__ void scan3_kernel(int* __restrict__ excl, const int* __restrict__ boff,
                             int* __restrict__ next) {
    int i = blockIdx.x * 256 + threadIdx.x;
    if (i < NN) {
        int s = excl[i] + boff[blockIdx.x];
        excl[i] = s;
        next[i] = s;
    }
}

__global__ void scatter_kernel(const int* __restrict__ src, const int* __restrict__ dst,
                               int* __restrict__ next, int* __restrict__ perm) {
    int e = blockIdx.x * blockDim.x + threadIdx.x;
    if (e < NE) {
        int s = __builtin_nontemporal_load(&src[e]);   // streaming reads: keep L2 for perm
        int d = __builtin_nontemporal_load(&dst[e]);
        int pos = atomicAdd(&next[d], 1);
        perm[pos] = s;                                 // normal store: let L2 absorb
    }
}

// ---------------- weight prep: BT1[j][k], BT2[j][k] bf16 (transposed, k-contig) --------
__global__ void wprep_kernel(const float* __restrict__ W1l, const float* __restrict__ W1r,
                             const float* __restrict__ W2l, const float* __restrict__ W2r,
                             unsigned short* __restrict__ BT1, unsigned short* __restrict__ BT2) {
    int idx = blockIdx.x * 256 + threadIdx.x;
    if (idx >= 128 * 128) return;
    int j = idx >> 7, k = idx & 127;
    float v1 = (k < 64) ? W1l[k * HID + j] : W1r[(k - 64) * HID + j];
    BT1[j * 128 + k] = f2bf(v1);
    float v2 = (j < 64) ? W2l[k * OUTD + j] : W2r[k * OUTD + (j - 64)];
    BT2[j * 128 + k] = f2bf(v2);
}

// ---------------- x -> bf16 into A1 cols [64:128) ----------------
__global__ void x2bf_kernel(const float* __restrict__ x, unsigned short* __restrict__ A1) {
    int idx = blockIdx.x * 256 + threadIdx.x;   // NN*16 float4 slots
    if (idx >= NN * 16) return;
    int n = idx >> 4, q = idx & 15;
    float4 v = ((const float4*)x)[idx];
    ushort4 o;
    o.x = f2bf(v.x); o.y = f2bf(v.y); o.z = f2bf(v.z); o.w = f2bf(v.w);
    *(ushort4*)(A1 + (size_t)n * 128 + 64 + q * 4) = o;
}

// ---------------- gather-aggregate over bf16 rows, one wave per node --------
// MODE 0: store bf16 mean into outb row; MODE 1: outf[n*64+c] += mean (fp32)
template<int MODE>
__global__ __launch_bounds__(256) void agg_gather_b(
    const unsigned short* __restrict__ feat, int fstride, int foff,
    const int* __restrict__ start, const int* __restrict__ perm,
    unsigned short* __restrict__ outb, int ostride, int ooff,
    float* __restrict__ outf)
{
    int wave = (blockIdx.x * blockDim.x + threadIdx.x) >> 6;
    if (wave >= NN) return;
    int lane = threadIdx.x & 63;
    int g = lane >> 3;        // 8 edge groups
    int q = lane & 7;         // 8 bf16 per slot
    int rs = start[wave];
    int re = (wave == NN - 1) ? NE : start[wave + 1];
    float acc[8];
#pragma unroll
    for (int t = 0; t < 8; t++) acc[t] = 0.f;
    for (int i = rs + g; i < re; i += 8) {
        int s = perm[i];
        uint4 v = *(const uint4*)(feat + (size_t)s * fstride + foff + q * 8);
        acc[0] += bflo(v.x); acc[1] += bfhi(v.x);
        acc[2] += bflo(v.y); acc[3] += bfhi(v.y);
        acc[4] += bflo(v.z); acc[5] += bfhi(v.z);
        acc[6] += bflo(v.w); acc[7] += bfhi(v.w);
    }
#pragma unroll
    for (int t = 0; t < 8; t++) {
        acc[t] += __shfl_xor(acc[t], 8, 64);
        acc[t] += __shfl_xor(acc[t], 16, 64);
        acc[t] += __shfl_xor(acc[t], 32, 64);
    }
    if (g == 0) {
        int cnt = re - rs;
        float inv = (cnt > 0) ? (1.0f / (float)cnt) : 0.f;
        if (MODE == 0) {
            uint4 o;
            o.x = (unsigned)f2bf(acc[0] * inv) | ((unsigned)f2bf(acc[1] * inv) << 16);
            o.y = (unsigned)f2bf(acc[2] * inv) | ((unsigned)f2bf(acc[3] * inv) << 16);
            o.z = (unsigned)f2bf(acc[4] * inv) | ((unsigned)f2bf(acc[5] * inv) << 16);
            o.w = (unsigned)f2bf(acc[6] * inv) | ((unsigned)f2bf(acc[7] * inv) << 16);
            *(uint4*)(outb + (size_t)wave * ostride + ooff + q * 8) = o;
        } else {
            float4* op = (float4*)(outf + (size_t)wave * 64 + q * 8);
            float4 o0 = op[0], o1 = op[1];
            o0.x += acc[0] * inv; o0.y += acc[1] * inv;
            o0.z += acc[2] * inv; o0.w += acc[3] * inv;
            o1.x += acc[4] * inv; o1.y += acc[5] * inv;
            o1.z += acc[6] * inv; o1.w += acc[7] * inv;
            op[0] = o0; op[1] = o1;
        }
    }
}

// ---------------- MFMA conv: B in registers, multi-tile per wave, A prefetch -------
template<bool IS1>
__global__ __launch_bounds__(256) void conv_mfma_kernel(
    const unsigned short* __restrict__ A, const unsigned short* __restrict__ BT,
    const float* __restrict__ bias,
    unsigned short* __restrict__ outb, float* __restrict__ outf,
    float* __restrict__ sums, float* __restrict__ sumsq)
{
    __shared__ float red_s[4][128];
    __shared__ float red_q[4][128];
    int tid = threadIdx.x;
    int wid = tid >> 6, lane = tid & 63;
    int m = lane & 15, ko = lane >> 4;
    int gw = blockIdx.x * 4 + wid;
    int jh = gw & 1;                       // j-half this wave owns
    int tstride = (gridDim.x * 4) >> 1;
    const int tiles = NN / 16;             // 3125, exact
    // preload B fragments for this j-half (16 x bf16x8 = 64 VGPRs)
    bf16x8 b[4][4];
    const unsigned short* bbase = BT + (size_t)(jh * 64 + m) * 128 + ko * 8;
#pragma unroll
    for (int jg = 0; jg < 4; jg++)
#pragma unroll
        for (int ks = 0; ks < 4; ks++)
            b[jg][ks] = *(const bf16x8*)(bbase + jg * 16 * 128 + ks * 32);
    float bj[4];
#pragma unroll
    for (int jg = 0; jg < 4; jg++)
        bj[jg] = IS1 ? bias[jh * 64 + jg * 16 + m] : (jh ? bias[jg * 16 + m] : 0.f);
    float s_sum[4] = {0.f, 0.f, 0.f, 0.f}, s_sq[4] = {0.f, 0.f, 0.f, 0.f};
    int tile = gw >> 1;
    bf16x8 a[4];
    if (tile < tiles) {
        const unsigned short* arow = A + (size_t)(tile * 16 + m) * 128 + ko * 8;
#pragma unroll
        for (int ks = 0; ks < 4; ks++) a[ks] = *(const bf16x8*)(arow + ks * 32);
    }
    while (tile < tiles) {
        int nxt = tile + tstride;
        bf16x8 an[4];
        if (nxt < tiles) {
            const unsigned short* arow = A + (size_t)(nxt * 16 + m) * 128 + ko * 8;
#pragma unroll
            for (int ks = 0; ks < 4; ks++) an[ks] = *(const bf16x8*)(arow + ks * 32);
        }
        int n0 = tile * 16;
#pragma unroll
        for (int jg = 0; jg < 4; jg++) {
            f32x4 acc = {0.f, 0.f, 0.f, 0.f};
#pragma unroll
            for (int ks = 0; ks < 4; ks++)
                acc = __builtin_amdgcn_mfma_f32_16x16x32_bf16(a[ks], b[jg][ks], acc, 0, 0, 0);
            int j = jh * 64 + jg * 16 + m;
#pragma unroll
            for (int r = 0; r < 4; r++) {
                int n = n0 + ko * 4 + r;
                float v = acc[r];
                if (IS1) {
                    v += bj[jg];
                    outb[(size_t)n * 128 + j] = f2bf(v);
                    s_sum[jg] += v;
                    s_sq[jg] += v * v;
                } else {
                    if (jh == 0) outb[(size_t)n * 64 + j] = f2bf(v);
                    else         outf[(size_t)n * 64 + (j - 64)] = v + bj[jg];
                }
            }
        }
#pragma unroll
        for (int ks = 0; ks < 4; ks++) a[ks] = an[ks];
        tile = nxt;
    }
    if (IS1) {
        for (int i = tid; i < 512; i += 256) {
            ((float*)red_s)[i] = 0.f;
            ((float*)red_q)[i] = 0.f;
        }
        __syncthreads();
#pragma unroll
        for (int jg = 0; jg < 4; jg++) {
            float v = s_sum[jg];
            v += __shfl_xor(v, 16, 64);
            v += __shfl_xor(v, 32, 64);
            float w = s_sq[jg];
            w += __shfl_xor(w, 16, 64);
            w += __shfl_xor(w, 32, 64);
            if (lane < 16) {
                red_s[wid][jh * 64 + jg * 16 + lane] = v;
                red_q[wid][jh * 64 + jg * 16 + lane] = w;
            }
        }
        __syncthreads();
        if (tid < 128) {
            float v = red_s[0][tid] + red_s[1][tid] + red_s[2][tid] + red_s[3][tid];
            atomicAdd(&sums[tid], v);
        } else {
            int j = tid - 128;
            float v = red_q[0][j] + red_q[1][j] + red_q[2][j] + red_q[3][j];
            atomicAdd(&sumsq[j], v);
        }
    }
}

// ---------------- BN stats -> scale/shift ----------------
__global__ void bnstat_kernel(const float* __restrict__ sums, const float* __restrict__ sumsq,
                              const float* __restrict__ gamma, const float* __restrict__ beta,
                              float* __restrict__ scale, float* __restrict__ shift) {
    int c = threadIdx.x;
    if (c < HID) {
        float inv_n = 1.0f / (float)NN;
        float mu = sums[c] * inv_n;
        float var = sumsq[c] * inv_n - mu * mu;
        float s = gamma[c] * rsqrtf(var + 1e-5f);
        scale[c] = s;
        shift[c] = beta[c] - mu * s;
    }
}

// ---------------- bn+relu apply: h = relu(bn(hpreb)) bf16 -> A1 ----------------
__global__ void bnapply_kernel(const unsigned short* __restrict__ hpreb,
                               const float* __restrict__ scale, const float* __restrict__ shift,
                               unsigned short* __restrict__ A1) {
    int idx = blockIdx.x * 256 + threadIdx.x;   // NN*16 octet slots
    if (idx >= NN * 16) return;
    int q = idx & 15;
    int j0 = q * 8;
    uint4 v = ((const uint4*)hpreb)[idx];
    float f[8];
    f[0] = bflo(v.x); f[1] = bfhi(v.x);
    f[2] = bflo(v.y); f[3] = bfhi(v.y);
    f[4] = bflo(v.z); f[5] = bfhi(v.z);
    f[6] = bflo(v.w); f[7] = bfhi(v.w);
#pragma unroll
    for (int t = 0; t < 8; t++) {
        float h = f[t] * scale[j0 + t] + shift[j0 + t];
        f[t] = h > 0.f ? h : 0.f;
    }
    uint4 o;
    o.x = (unsigned)f2bf(f[0]) | ((unsigned)f2bf(f[1]) << 16);
    o.y = (unsigned)f2bf(f[2]) | ((unsigned)f2bf(f[3]) << 16);
    o.z = (unsigned)f2bf(f[4]) | ((unsigned)f2bf(f[5]) << 16);
    o.w = (unsigned)f2bf(f[6]) | ((unsigned)f2bf(f[7]) << 16);
    ((uint4*)A1)[idx] = o;
}

extern "C" void kernel_launch(void* const* d_in, const int* in_sizes, int n_in,
                              void* d_out, int out_size, void* d_ws, size_t ws_size,
                              hipStream_t stream) {
    const float* x     = (const float*)d_in[0];
    const int*   ei    = (const int*)d_in[1];
    const float* W1l   = (const float*)d_in[2];
    const float* b1    = (const float*)d_in[3];
    const float* W1r   = (const float*)d_in[4];
    const float* gamma = (const float*)d_in[5];
    const float* beta  = (const float*)d_in[6];
    const float* W2l   = (const float*)d_in[7];
    const float* b2    = (const float*)d_in[8];
    const float* W2r   = (const float*)d_in[9];
    float* out = (float*)d_out;

    // workspace layout (~29.3 MB, proven-safe budget)
    char* wsb = (char*)d_ws;
    int*   cnt    = (int*)wsb;                                  // NN
    int*   startp = cnt + NN;                                   // NN
    int*   bsum   = cnt + 2 * NN;                               // 256
    int*   boff   = bsum + 256;                                 // 256
    int*   perm   = boff + 256;                                 // NE
    unsigned short* A1    = (unsigned short*)(perm + NE);       // NN*128 bf16
    unsigned short* hpreb = A1 + (size_t)NN * 128;              // NN*128 bf16; reused as pb
    unsigned short* BT1   = hpreb + (size_t)NN * 128;           // 128*128 bf16
    unsigned short* BT2   = BT1 + 128 * 128;                    // 128*128 bf16
    float* sums  = (float*)(BT2 + 128 * 128);                   // 128
    float* sumsq = sums + 128;                                  // 128
    float* scale = sums + 256;                                  // 128
    float* shift = sums + 384;                                  // 128

    const int* srcp = ei;
    const int* dstp = ei + NE;

    hipMemsetAsync(cnt, 0, sizeof(int) * NN, stream);
    hipMemsetAsync(sums, 0, sizeof(float) * 256, stream);

    const int EB = (NE + 255) / 256;
    const int SB = (NN + 255) / 256;
    const int GB = (NN * 64 + 255) / 256;   // one wave per node
    const int XB = (NN * 16 + 255) / 256;
    const int CB = 512;                     // 2048 waves, ~3 tiles each + prefetch

    hist_kernel<<<EB, 256, 0, stream>>>(dstp, cnt);
    scan1_kernel<<<SB, 256, 0, stream>>>(cnt, startp, bsum);
    scan2_kernel<<<1, 256, 0, stream>>>(bsum, boff, SB);
    scan3_kernel<<<SB, 256, 0, stream>>>(startp, boff, cnt);
    scatter_kernel<<<EB, 256, 0, stream>>>(srcp, dstp, cnt, perm);

    wprep_kernel<<<64, 256, 0, stream>>>(W1l, W1r, W2l, W2r, BT1, BT2);
    x2bf_kernel<<<XB, 256, 0, stream>>>(x, A1);

    // agg1: gather A1 x-half (cols 64:128) -> bf16 mean into A1 cols 0:64
    agg_gather_b<0><<<GB, 256, 0, stream>>>(A1, 128, 64, startp, perm, A1, 128, 0, nullptr);
    // conv1: hpre = A1 @ [W1l;W1r] + b1 ; bf16 store + fp32 BN stats
    conv_mfma_kernel<true><<<CB, 256, 0, stream>>>(A1, BT1, b1, hpreb, nullptr, sums, sumsq);
    bnstat_kernel<<<1, 128, 0, stream>>>(sums, sumsq, gamma, beta, scale, shift);
    // h = relu(bn(hpreb)) -> A1
    bnapply_kernel<<<XB, 256, 0, stream>>>(hpreb, scale, shift, A1);
    // conv2: [p | self] = A1 @ [W2l|W2r] ; p bf16 -> hpreb(=pb), self+b2 -> out
    conv_mfma_kernel<false><<<CB, 256, 0, stream>>>(A1, BT2, b2, hpreb, out, nullptr, nullptr);
    // agg2: gather pb rows -> out += mean
    agg_gather_b<1><<<GB, 256, 0, stream>>>(hpreb, 64, 0, startp, perm, nullptr, 0, 0, out);
}

// Round 12
// 259.312 us; speedup vs baseline: 1.9861x; 1.0504x over previous
//
#include <hip/hip_runtime.h>

#define NN 50000
#define NE 800000
#define HID 128
#define OUTD 64
#define NBK 200      // buckets for two-phase scatter
#define BWID 250     // nodes per bucket (NN/NBK exact)
#define TILE_E 4096  // edges per binA block

typedef __attribute__((ext_vector_type(8))) short bf16x8;
typedef __attribute__((ext_vector_type(4))) float f32x4;

static __device__ __forceinline__ unsigned short f2bf(float f) {
    unsigned u = __float_as_uint(f);
    unsigned r = (u + 0x7FFFu + ((u >> 16) & 1u)) >> 16;   // RNE
    return (unsigned short)r;
}
static __device__ __forceinline__ float bflo(unsigned u) { return __uint_as_float(u << 16); }
static __device__ __forceinline__ float bfhi(unsigned u) { return __uint_as_float(u & 0xffff0000u); }

// ---------------- CSR build ----------------
__global__ void hist_kernel(const int* __restrict__ dst, int* __restrict__ cnt) {
    int e = blockIdx.x * blockDim.x + threadIdx.x;
    if (e < NE) {
        int d = __builtin_nontemporal_load(&dst[e]);
        atomicAdd(&cnt[d], 1);
    }
}

__global__ void scan1_kernel(const int* __restrict__ cnt, int* __restrict__ excl,
                             int* __restrict__ bsum) {
    __shared__ int tmp[256];
    int tid = threadIdx.x;
    int i = blockIdx.x * 256 + tid;
    int v = (i < NN) ? cnt[i] : 0;
    tmp[tid] = v;
    __syncthreads();
    for (int off = 1; off < 256; off <<= 1) {
        int t = (tid >= off) ? tmp[tid - off] : 0;
        __syncthreads();
        tmp[tid] += t;
        __syncthreads();
    }
    if (i < NN) excl[i] = tmp[tid] - v;
    if (tid == 255) bsum[blockIdx.x] = tmp[255];
}

__global__ void scan2_kernel(int* __restrict__ bsum, int* __restrict__ boff, int nb) {
    __shared__ int tmp[256];
    int tid = threadIdx.x;
    int v = (tid < nb) ? bsum[tid] : 0;
    tmp[tid] = v;
    __syncthreads();
    for (int off = 1; off < 256; off <<= 1) {
        int t = (tid >= off) ? tmp[tid - off] : 0;
        __syncthreads();
        tmp[tid] += t;
        __syncthreads();
    }
    if (tid < nb) boff[tid] = tmp[tid] - v;
}

__global__ void scan3_kernel(int* __restrict__ excl, const int* __restrict__ boff,
                             int* __restrict__ next) {
    int i = blockIdx.x * 256 + threadIdx.x;
    if (i < NN) {
        int s = excl[i] + boff[blockIdx.x];
        excl[i] = s;
        next[i] = s;
    }
}

// bucket cursors from CSR starts (one global atomic target per bucket)
__global__ void initcur_kernel(const int* __restrict__ startp, int* __restrict__ gcur) {
    int b = threadIdx.x;
    if (b < NBK) gcur[b] = startp[b * BWID];
}

// ---------------- phase A: bin edges into bucket-grouped pairs ----------------
// Per-bucket global atomics happen once per BLOCK (39k total), not per edge.
__global__ __launch_bounds__(256) void binA_kernel(const int* __restrict__ src,
                                                   const int* __restrict__ dst,
                                                   int* __restrict__ gcur,
                                                   int2* __restrict__ pairs) {
    __shared__ int lcnt[NBK];
    __shared__ int lbase[NBK];
    int tid = threadIdx.x;
    int e0 = blockIdx.x * TILE_E;
    for (int i = tid; i < NBK; i += 256) lcnt[i] = 0;
    __syncthreads();
    int s[16], d[16], loc[16];
#pragma unroll
    for (int i = 0; i < 16; i++) {
        int e = e0 + i * 256 + tid;
        if (e < NE) {
            s[i] = __builtin_nontemporal_load(&src[e]);
            d[i] = __builtin_nontemporal_load(&dst[e]);
            loc[i] = atomicAdd(&lcnt[d[i] / BWID], 1);
        }
    }
    __syncthreads();
    for (int b = tid; b < NBK; b += 256)
        lbase[b] = atomicAdd(&gcur[b], lcnt[b]);
    __syncthreads();
#pragma unroll
    for (int i = 0; i < 16; i++) {
        int e = e0 + i * 256 + tid;
        if (e < NE)
            pairs[lbase[d[i] / BWID] + loc[i]] = make_int2(s[i], d[i]);
    }
}

// ---------------- phase B: bucket-grouped pairs -> CSR perm ----------------
// One block per bucket: each 16KB perm window owned by a single block/XCD.
__global__ __launch_bounds__(256) void binB_kernel(const int2* __restrict__ pairs,
                                                   const int* __restrict__ startp,
                                                   int* __restrict__ next,
                                                   int* __restrict__ perm) {
    int b = blockIdx.x;
    int lo = startp[b * BWID];
    int hi = (b == NBK - 1) ? NE : startp[(b + 1) * BWID];
    for (int i = lo + threadIdx.x; i < hi; i += 256) {
        int2 p = pairs[i];
        int pos = atomicAdd(&next[p.y], 1);
        perm[pos] = p.x;
    }
}

// ---------------- weight prep: BT1[j][k], BT2[j][k] bf16 (transposed, k-contig) --------
__global__ void wprep_kernel(const float* __restrict__ W1l, const float* __restrict__ W1r,
                             const float* __restrict__ W2l, const float* __restrict__ W2r,
                             unsigned short* __restrict__ BT1, unsigned short* __restrict__ BT2) {
    int idx = blockIdx.x * 256 + threadIdx.x;
    if (idx >= 128 * 128) return;
    int j = idx >> 7, k = idx & 127;
    float v1 = (k < 64) ? W1l[k * HID + j] : W1r[(k - 64) * HID + j];
    BT1[j * 128 + k] = f2bf(v1);
    float v2 = (j < 64) ? W2l[k * OUTD + j] : W2r[k * OUTD + (j - 64)];
    BT2[j * 128 + k] = f2bf(v2);
}

// ---------------- x -> bf16 into A1 cols [64:128) ----------------
__global__ void x2bf_kernel(const float* __restrict__ x, unsigned short* __restrict__ A1) {
    int idx = blockIdx.x * 256 + threadIdx.x;   // NN*16 float4 slots
    if (idx >= NN * 16) return;
    int n = idx >> 4, q = idx & 15;
    float4 v = ((const float4*)x)[idx];
    ushort4 o;
    o.x = f2bf(v.x); o.y = f2bf(v.y); o.z = f2bf(v.z); o.w = f2bf(v.w);
    *(ushort4*)(A1 + (size_t)n * 128 + 64 + q * 4) = o;
}

// ---------------- gather-aggregate over bf16 rows, one wave per node --------
// 2x unrolled: two independent row-loads in flight per lane.
// MODE 0: store bf16 mean into outb row; MODE 1: outf[n*64+c] += mean (fp32)
template<int MODE>
__global__ __launch_bounds__(256) void agg_gather_b(
    const unsigned short* __restrict__ feat, int fstride, int foff,
    const int* __restrict__ start, const int* __restrict__ perm,
    unsigned short* __restrict__ outb, int ostride, int ooff,
    float* __restrict__ outf)
{
    int wave = (blockIdx.x * blockDim.x + threadIdx.x) >> 6;
    if (wave >= NN) return;
    int lane = threadIdx.x & 63;
    int g = lane >> 3;        // 8 edge groups
    int q = lane & 7;         // 8 bf16 per slot
    int rs = start[wave];
    int re = (wave == NN - 1) ? NE : start[wave + 1];
    float acc[8];
#pragma unroll
    for (int t = 0; t < 8; t++) acc[t] = 0.f;
    int i = rs + g;
    for (; i + 8 < re; i += 16) {
        int s0 = perm[i];
        int s1 = perm[i + 8];
        uint4 v0 = *(const uint4*)(feat + (size_t)s0 * fstride + foff + q * 8);
        uint4 v1 = *(const uint4*)(feat + (size_t)s1 * fstride + foff + q * 8);
        acc[0] += bflo(v0.x); acc[1] += bfhi(v0.x);
        acc[2] += bflo(v0.y); acc[3] += bfhi(v0.y);
        acc[4] += bflo(v0.z); acc[5] += bfhi(v0.z);
        acc[6] += bflo(v0.w); acc[7] += bfhi(v0.w);
        acc[0] += bflo(v1.x); acc[1] += bfhi(v1.x);
        acc[2] += bflo(v1.y); acc[3] += bfhi(v1.y);
        acc[4] += bflo(v1.z); acc[5] += bfhi(v1.z);
        acc[6] += bflo(v1.w); acc[7] += bfhi(v1.w);
    }
    if (i < re) {
        int s0 = perm[i];
        uint4 v0 = *(const uint4*)(feat + (size_t)s0 * fstride + foff + q * 8);
        acc[0] += bflo(v0.x); acc[1] += bfhi(v0.x);
        acc[2] += bflo(v0.y); acc[3] += bfhi(v0.y);
        acc[4] += bflo(v0.z); acc[5] += bfhi(v0.z);
        acc[6] += bflo(v0.w); acc[7] += bfhi(v0.w);
    }
#pragma unroll
    for (int t = 0; t < 8; t++) {
        acc[t] += __shfl_xor(acc[t], 8, 64);
        acc[t] += __shfl_xor(acc[t], 16, 64);
        acc[t] += __shfl_xor(acc[t], 32, 64);
    }
    if (g == 0) {
        int cnt = re - rs;
        float inv = (cnt > 0) ? (1.0f / (float)cnt) : 0.f;
        if (MODE == 0) {
            uint4 o;
            o.x = (unsigned)f2bf(acc[0] * inv) | ((unsigned)f2bf(acc[1] * inv) << 16);
            o.y = (unsigned)f2bf(acc[2] * inv) | ((unsigned)f2bf(acc[3] * inv) << 16);
            o.z = (unsigned)f2bf(acc[4] * inv) | ((unsigned)f2bf(acc[5] * inv) << 16);
            o.w = (unsigned)f2bf(acc[6] * inv) | ((unsigned)f2bf(acc[7] * inv) << 16);
            *(uint4*)(outb + (size_t)wave * ostride + ooff + q * 8) = o;
        } else {
            float4* op = (float4*)(outf + (size_t)wave * 64 + q * 8);
            float4 o0 = op[0], o1 = op[1];
            o0.x += acc[0] * inv; o0.y += acc[1] * inv;
            o0.z += acc[2] * inv; o0.w += acc[3] * inv;
            o1.x += acc[4] * inv; o1.y += acc[5] * inv;
            o1.z += acc[6] * inv; o1.w += acc[7] * inv;
            op[0] = o0; op[1] = o1;
        }
    }
}

// ---------------- MFMA conv: B in registers, multi-tile per wave, A prefetch -------
template<bool IS1>
__global__ __launch_bounds__(256) void conv_mfma_kernel(
    const unsigned short* __restrict__ A, const unsigned short* __restrict__ BT,
    const float* __restrict__ bias,
    unsigned short* __restrict__ outb, float* __restrict__ outf,
    float* __restrict__ sums, float* __restrict__ sumsq)
{
    __shared__ float red_s[4][128];
    __shared__ float red_q[4][128];
    int tid = threadIdx.x;
    int wid = tid >> 6, lane = tid & 63;
    int m = lane & 15, ko = lane >> 4;
    int gw = blockIdx.x * 4 + wid;
    int jh = gw & 1;                       // j-half this wave owns
    int tstride = (gridDim.x * 4) >> 1;
    const int tiles = NN / 16;             // 3125, exact
    // preload B fragments for this j-half (16 x bf16x8 = 64 VGPRs)
    bf16x8 b[4][4];
    const unsigned short* bbase = BT + (size_t)(jh * 64 + m) * 128 + ko * 8;
#pragma unroll
    for (int jg = 0; jg < 4; jg++)
#pragma unroll
        for (int ks = 0; ks < 4; ks++)
            b[jg][ks] = *(const bf16x8*)(bbase + jg * 16 * 128 + ks * 32);
    float bj[4];
#pragma unroll
    for (int jg = 0; jg < 4; jg++)
        bj[jg] = IS1 ? bias[jh * 64 + jg * 16 + m] : (jh ? bias[jg * 16 + m] : 0.f);
    float s_sum[4] = {0.f, 0.f, 0.f, 0.f}, s_sq[4] = {0.f, 0.f, 0.f, 0.f};
    int tile = gw >> 1;
    bf16x8 a[4];
    if (tile < tiles) {
        const unsigned short* arow = A + (size_t)(tile * 16 + m) * 128 + ko * 8;
#pragma unroll
        for (int ks = 0; ks < 4; ks++) a[ks] = *(const bf16x8*)(arow + ks * 32);
    }
    while (tile < tiles) {
        int nxt = tile + tstride;
        bf16x8 an[4];
        if (nxt < tiles) {
            const unsigned short* arow = A + (size_t)(nxt * 16 + m) * 128 + ko * 8;
#pragma unroll
            for (int ks = 0; ks < 4; ks++) an[ks] = *(const bf16x8*)(arow + ks * 32);
        }
        int n0 = tile * 16;
#pragma unroll
        for (int jg = 0; jg < 4; jg++) {
            f32x4 acc = {0.f, 0.f, 0.f, 0.f};
#pragma unroll
            for (int ks = 0; ks < 4; ks++)
                acc = __builtin_amdgcn_mfma_f32_16x16x32_bf16(a[ks], b[jg][ks], acc, 0, 0, 0);
            int j = jh * 64 + jg * 16 + m;
#pragma unroll
            for (int r = 0; r < 4; r++) {
                int n = n0 + ko * 4 + r;
                float v = acc[r];
                if (IS1) {
                    v += bj[jg];
                    outb[(size_t)n * 128 + j] = f2bf(v);
                    s_sum[jg] += v;
                    s_sq[jg] += v * v;
                } else {
                    if (jh == 0) outb[(size_t)n * 64 + j] = f2bf(v);
                    else         outf[(size_t)n * 64 + (j - 64)] = v + bj[jg];
                }
            }
        }
#pragma unroll
        for (int ks = 0; ks < 4; ks++) a[ks] = an[ks];
        tile = nxt;
    }
    if (IS1) {
        for (int i = tid; i < 512; i += 256) {
            ((float*)red_s)[i] = 0.f;
            ((float*)red_q)[i] = 0.f;
        }
        __syncthreads();
#pragma unroll
        for (int jg = 0; jg < 4; jg++) {
            float v = s_sum[jg];
            v += __shfl_xor(v, 16, 64);
            v += __shfl_xor(v, 32, 64);
            float w = s_sq[jg];
            w += __shfl_xor(w, 16, 64);
            w += __shfl_xor(w, 32, 64);
            if (lane < 16) {
                red_s[wid][jh * 64 + jg * 16 + lane] = v;
                red_q[wid][jh * 64 + jg * 16 + lane] = w;
            }
        }
        __syncthreads();
        if (tid < 128) {
            float v = red_s[0][tid] + red_s[1][tid] + red_s[2][tid] + red_s[3][tid];
            atomicAdd(&sums[tid], v);
        } else {
            int j = tid - 128;
            float v = red_q[0][j] + red_q[1][j] + red_q[2][j] + red_q[3][j];
            atomicAdd(&sumsq[j], v);
        }
    }
}

// ---------------- BN stats -> scale/shift ----------------
__global__ void bnstat_kernel(const float* __restrict__ sums, const float* __restrict__ sumsq,
                              const float* __restrict__ gamma, const float* __restrict__ beta,
                              float* __restrict__ scale, float* __restrict__ shift) {
    int c = threadIdx.x;
    if (c < HID) {
        float inv_n = 1.0f / (float)NN;
        float mu = sums[c] * inv_n;
        float var = sumsq[c] * inv_n - mu * mu;
        float s = gamma[c] * rsqrtf(var + 1e-5f);
        scale[c] = s;
        shift[c] = beta[c] - mu * s;
    }
}

// ---------------- bn+relu apply: h = relu(bn(hpreb)) bf16 -> A1 ----------------
__global__ void bnapply_kernel(const unsigned short* __restrict__ hpreb,
                               const float* __restrict__ scale, const float* __restrict__ shift,
                               unsigned short* __restrict__ A1) {
    int idx = blockIdx.x * 256 + threadIdx.x;   // NN*16 octet slots
    if (idx >= NN * 16) return;
    int q = idx & 15;
    int j0 = q * 8;
    uint4 v = ((const uint4*)hpreb)[idx];
    float f[8];
    f[0] = bflo(v.x); f[1] = bfhi(v.x);
    f[2] = bflo(v.y); f[3] = bfhi(v.y);
    f[4] = bflo(v.z); f[5] = bfhi(v.z);
    f[6] = bflo(v.w); f[7] = bfhi(v.w);
#pragma unroll
    for (int t = 0; t < 8; t++) {
        float h = f[t] * scale[j0 + t] + shift[j0 + t];
        f[t] = h > 0.f ? h : 0.f;
    }
    uint4 o;
    o.x = (unsigned)f2bf(f[0]) | ((unsigned)f2bf(f[1]) << 16);
    o.y = (unsigned)f2bf(f[2]) | ((unsigned)f2bf(f[3]) << 16);
    o.z = (unsigned)f2bf(f[4]) | ((unsigned)f2bf(f[5]) << 16);
    o.w = (unsigned)f2bf(f[6]) | ((unsigned)f2bf(f[7]) << 16);
    ((uint4*)A1)[idx] = o;
}

extern "C" void kernel_launch(void* const* d_in, const int* in_sizes, int n_in,
                              void* d_out, int out_size, void* d_ws, size_t ws_size,
                              hipStream_t stream) {
    const float* x     = (const float*)d_in[0];
    const int*   ei    = (const int*)d_in[1];
    const float* W1l   = (const float*)d_in[2];
    const float* b1    = (const float*)d_in[3];
    const float* W1r   = (const float*)d_in[4];
    const float* gamma = (const float*)d_in[5];
    const float* beta  = (const float*)d_in[6];
    const float* W2l   = (const float*)d_in[7];
    const float* b2    = (const float*)d_in[8];
    const float* W2r   = (const float*)d_in[9];
    float* out = (float*)d_out;

    // workspace layout (~35.7 MB; <= R1's proven 38.6 MB budget)
    char* wsb = (char*)d_ws;
    int*   cnt    = (int*)wsb;                                  // NN (CSR cursor after scan3)
    int*   startp = cnt + NN;                                   // NN
    int*   bsum   = cnt + 2 * NN;                               // 256
    int*   boff   = bsum + 256;                                 // 256
    int*   gcur   = boff + 256;                                 // 256 (bucket cursors)
    int*   perm   = gcur + 256;                                 // NE
    int2*  pairs  = (int2*)(perm + NE);                         // NE int2 (6.4 MB)
    unsigned short* A1    = (unsigned short*)(pairs + NE);      // NN*128 bf16
    unsigned short* hpreb = A1 + (size_t)NN * 128;              // NN*128 bf16; reused as pb
    unsigned short* BT1   = hpreb + (size_t)NN * 128;           // 128*128 bf16
    unsigned short* BT2   = BT1 + 128 * 128;                    // 128*128 bf16
    float* sums  = (float*)(BT2 + 128 * 128);                   // 128
    float* sumsq = sums + 128;                                  // 128
    float* scale = sums + 256;                                  // 128
    float* shift = sums + 384;                                  // 128

    const int* srcp = ei;
    const int* dstp = ei + NE;

    hipMemsetAsync(cnt, 0, sizeof(int) * NN, stream);
    hipMemsetAsync(sums, 0, sizeof(float) * 256, stream);

    const int EB = (NE + 255) / 256;
    const int SB = (NN + 255) / 256;
    const int GB = (NN * 64 + 255) / 256;   // one wave per node
    const int XB = (NN * 16 + 255) / 256;
    const int CB = 512;                     // conv grid
    const int AB = (NE + TILE_E - 1) / TILE_E;   // 196 binA blocks

    hist_kernel<<<EB, 256, 0, stream>>>(dstp, cnt);
    scan1_kernel<<<SB, 256, 0, stream>>>(cnt, startp, bsum);
    scan2_kernel<<<1, 256, 0, stream>>>(bsum, boff, SB);
    scan3_kernel<<<SB, 256, 0, stream>>>(startp, boff, cnt);   // cnt becomes CSR cursor
    initcur_kernel<<<1, 256, 0, stream>>>(startp, gcur);
    binA_kernel<<<AB, 256, 0, stream>>>(srcp, dstp, gcur, pairs);
    binB_kernel<<<NBK, 256, 0, stream>>>(pairs, startp, cnt, perm);

    wprep_kernel<<<64, 256, 0, stream>>>(W1l, W1r, W2l, W2r, BT1, BT2);
    x2bf_kernel<<<XB, 256, 0, stream>>>(x, A1);

    // agg1: gather A1 x-half (cols 64:128) -> bf16 mean into A1 cols 0:64
    agg_gather_b<0><<<GB, 256, 0, stream>>>(A1, 128, 64, startp, perm, A1, 128, 0, nullptr);
    // conv1: hpre = A1 @ [W1l;W1r] + b1 ; bf16 store + fp32 BN stats
    conv_mfma_kernel<true><<<CB, 256, 0, stream>>>(A1, BT1, b1, hpreb, nullptr, sums, sumsq);
    bnstat_kernel<<<1, 128, 0, stream>>>(sums, sumsq, gamma, beta, scale, shift);
    // h = relu(bn(hpreb)) -> A1
    bnapply_kernel<<<XB, 256, 0, stream>>>(hpreb, scale, shift, A1);
    // conv2: [p | self] = A1 @ [W2l|W2r] ; p bf16 -> hpreb(=pb), self+b2 -> out
    conv_mfma_kernel<false><<<CB, 256, 0, stream>>>(A1, BT2, b2, hpreb, out, nullptr, nullptr);
    // agg2: gather pb rows -> out += mean
    agg_gather_b<1><<<GB, 256, 0, stream>>>(hpreb, 64, 0, startp, perm, nullptr, 0, 0, out);
}

// Round 13
// 223.303 us; speedup vs baseline: 2.3064x; 1.1613x over previous
//
#include <hip/hip_runtime.h>

#define NN 50000
#define NE 800000
#define HID 128
#define OUTD 64
#define NBK 200      // buckets (dst-partition) for two-phase scatter
#define BWID 250     // nodes per bucket (NN/NBK exact)
#define TILE_E 4096  // edges per binA/hist block
#define XB 3125      // NN*16/256 exact (x2bf blocks)
#define HB 196       // ceil(NE/TILE_E)

typedef __attribute__((ext_vector_type(8))) short bf16x8;
typedef __attribute__((ext_vector_type(4))) float f32x4;

static __device__ __forceinline__ unsigned short f2bf(float f) {
    unsigned u = __float_as_uint(f);
    unsigned r = (u + 0x7FFFu + ((u >> 16) & 1u)) >> 16;   // RNE
    return (unsigned short)r;
}
static __device__ __forceinline__ float bflo(unsigned u) { return __uint_as_float(u << 16); }
static __device__ __forceinline__ float bfhi(unsigned u) { return __uint_as_float(u & 0xffff0000u); }

// ---------------- fused prep: x2bf | wprep | bucket-hist ----------------
__global__ __launch_bounds__(256) void prep_kernel(
    const float* __restrict__ x, unsigned short* __restrict__ A1,
    const float* __restrict__ W1l, const float* __restrict__ W1r,
    const float* __restrict__ W2l, const float* __restrict__ W2r,
    unsigned short* __restrict__ BT1, unsigned short* __restrict__ BT2,
    const int* __restrict__ dst, int* __restrict__ bcnt)
{
    __shared__ int lcnt[NBK];
    int blk = blockIdx.x;
    int tid = threadIdx.x;
    if (blk < XB) {
        // x -> bf16 into A1 cols [64:128)
        int idx = blk * 256 + tid;
        int n = idx >> 4, q = idx & 15;
        float4 v = ((const float4*)x)[idx];
        ushort4 o;
        o.x = f2bf(v.x); o.y = f2bf(v.y); o.z = f2bf(v.z); o.w = f2bf(v.w);
        *(ushort4*)(A1 + (size_t)n * 128 + 64 + q * 4) = o;
    } else if (blk < XB + 64) {
        // weight prep: BT1[j][k], BT2[j][k] bf16 (transposed, k-contig)
        int idx = (blk - XB) * 256 + tid;
        int j = idx >> 7, k = idx & 127;
        float v1 = (k < 64) ? W1l[k * HID + j] : W1r[(k - 64) * HID + j];
        BT1[j * 128 + k] = f2bf(v1);
        float v2 = (j < 64) ? W2l[k * OUTD + j] : W2r[k * OUTD + (j - 64)];
        BT2[j * 128 + k] = f2bf(v2);
    } else {
        // bucket histogram over dst (LDS-aggregated; 200 global atomics/block)
        int hb = blk - XB - 64;
        for (int i = tid; i < NBK; i += 256) lcnt[i] = 0;
        __syncthreads();
        int e0 = hb * TILE_E;
#pragma unroll
        for (int i = 0; i < 16; i++) {
            int e = e0 + i * 256 + tid;
            if (e < NE) {
                int d = __builtin_nontemporal_load(&dst[e]);
                atomicAdd(&lcnt[d / BWID], 1);
            }
        }
        __syncthreads();
        for (int b = tid; b < NBK; b += 256)
            if (lcnt[b]) atomicAdd(&bcnt[b], lcnt[b]);
    }
}

// ---------------- scan 200 bucket counts -> gstart[0..200], gcur ----------------
__global__ void scanB_kernel(const int* __restrict__ bcnt, int* __restrict__ gstart,
                             int* __restrict__ gcur) {
    __shared__ int tmp[256];
    int tid = threadIdx.x;
    int v = (tid < NBK) ? bcnt[tid] : 0;
    tmp[tid] = v;
    __syncthreads();
    for (int off = 1; off < 256; off <<= 1) {
        int t = (tid >= off) ? tmp[tid - off] : 0;
        __syncthreads();
        tmp[tid] += t;
        __syncthreads();
    }
    if (tid < NBK) {
        int s = tmp[tid] - v;
        gstart[tid] = s;
        gcur[tid] = s;
    }
    if (tid == 0) gstart[NBK] = NE;
}

// ---------------- phase A: bin edges into bucket-grouped pairs ----------------
__global__ __launch_bounds__(256) void binA_kernel(const int* __restrict__ src,
                                                   const int* __restrict__ dst,
                                                   int* __restrict__ gcur,
                                                   int2* __restrict__ pairs) {
    __shared__ int lcnt[NBK];
    __shared__ int lbase[NBK];
    int tid = threadIdx.x;
    int e0 = blockIdx.x * TILE_E;
    for (int i = tid; i < NBK; i += 256) lcnt[i] = 0;
    __syncthreads();
    int s[16], d[16], loc[16];
#pragma unroll
    for (int i = 0; i < 16; i++) {
        int e = e0 + i * 256 + tid;
        if (e < NE) {
            s[i] = __builtin_nontemporal_load(&src[e]);
            d[i] = __builtin_nontemporal_load(&dst[e]);
            loc[i] = atomicAdd(&lcnt[d[i] / BWID], 1);
        }
    }
    __syncthreads();
    for (int b = tid; b < NBK; b += 256)
        lbase[b] = atomicAdd(&gcur[b], lcnt[b]);
    __syncthreads();
#pragma unroll
    for (int i = 0; i < 16; i++) {
        int e = e0 + i * 256 + tid;
        if (e < NE)
            pairs[lbase[d[i] / BWID] + loc[i]] = make_int2(s[i], d[i]);
    }
}

// ---------------- phase B: per-bucket local CSR build + perm scatter (LDS atomics) ----
__global__ __launch_bounds__(256) void binB_kernel(const int2* __restrict__ pairs,
                                                   const int* __restrict__ gstart,
                                                   int* __restrict__ startp,
                                                   int* __restrict__ perm) {
    __shared__ int lcnt[BWID];
    __shared__ int tmp[256];
    __shared__ int lcur[BWID];
    int b = blockIdx.x, tid = threadIdx.x;
    int lo = gstart[b], hi = gstart[b + 1];
    int base = b * BWID;
    for (int i = tid; i < BWID; i += 256) lcnt[i] = 0;
    __syncthreads();
    for (int i = lo + tid; i < hi; i += 256)
        atomicAdd(&lcnt[pairs[i].y - base], 1);
    __syncthreads();
    int v = (tid < BWID) ? lcnt[tid] : 0;
    tmp[tid] = v;
    __syncthreads();
    for (int off = 1; off < 256; off <<= 1) {
        int t = (tid >= off) ? tmp[tid - off] : 0;
        __syncthreads();
        tmp[tid] += t;
        __syncthreads();
    }
    if (tid < BWID) {
        int s = lo + tmp[tid] - v;   // global CSR start for node base+tid
        lcur[tid] = s;
        startp[base + tid] = s;
    }
    __syncthreads();
    for (int i = lo + tid; i < hi; i += 256) {
        int2 p = pairs[i];
        int pos = atomicAdd(&lcur[p.y - base], 1);
        perm[pos] = p.x;
    }
}

// ---------------- gather-aggregate over bf16 rows, one wave per node --------
// MODE 0: store bf16 mean into outb row; MODE 1: outf[n*64+c] += mean (fp32)
template<int MODE>
__global__ __launch_bounds__(256) void agg_gather_b(
    const unsigned short* __restrict__ feat, int fstride, int foff,
    const int* __restrict__ start, const int* __restrict__ perm,
    unsigned short* __restrict__ outb, int ostride, int ooff,
    float* __restrict__ outf)
{
    int wave = (blockIdx.x * blockDim.x + threadIdx.x) >> 6;
    if (wave >= NN) return;
    int lane = threadIdx.x & 63;
    int g = lane >> 3;        // 8 edge groups
    int q = lane & 7;         // 8 bf16 per slot
    int rs = start[wave];
    int re = (wave == NN - 1) ? NE : start[wave + 1];
    float acc[8];
#pragma unroll
    for (int t = 0; t < 8; t++) acc[t] = 0.f;
    int i = rs + g;
    for (; i + 8 < re; i += 16) {
        int s0 = perm[i];
        int s1 = perm[i + 8];
        uint4 v0 = *(const uint4*)(feat + (size_t)s0 * fstride + foff + q * 8);
        uint4 v1 = *(const uint4*)(feat + (size_t)s1 * fstride + foff + q * 8);
        acc[0] += bflo(v0.x); acc[1] += bfhi(v0.x);
        acc[2] += bflo(v0.y); acc[3] += bfhi(v0.y);
        acc[4] += bflo(v0.z); acc[5] += bfhi(v0.z);
        acc[6] += bflo(v0.w); acc[7] += bfhi(v0.w);
        acc[0] += bflo(v1.x); acc[1] += bfhi(v1.x);
        acc[2] += bflo(v1.y); acc[3] += bfhi(v1.y);
        acc[4] += bflo(v1.z); acc[5] += bfhi(v1.z);
        acc[6] += bflo(v1.w); acc[7] += bfhi(v1.w);
    }
    if (i < re) {
        int s0 = perm[i];
        uint4 v0 = *(const uint4*)(feat + (size_t)s0 * fstride + foff + q * 8);
        acc[0] += bflo(v0.x); acc[1] += bfhi(v0.x);
        acc[2] += bflo(v0.y); acc[3] += bfhi(v0.y);
        acc[4] += bflo(v0.z); acc[5] += bfhi(v0.z);
        acc[6] += bflo(v0.w); acc[7] += bfhi(v0.w);
    }
#pragma unroll
    for (int t = 0; t < 8; t++) {
        acc[t] += __shfl_xor(acc[t], 8, 64);
        acc[t] += __shfl_xor(acc[t], 16, 64);
        acc[t] += __shfl_xor(acc[t], 32, 64);
    }
    if (g == 0) {
        int cnt = re - rs;
        float inv = (cnt > 0) ? (1.0f / (float)cnt) : 0.f;
        if (MODE == 0) {
            uint4 o;
            o.x = (unsigned)f2bf(acc[0] * inv) | ((unsigned)f2bf(acc[1] * inv) << 16);
            o.y = (unsigned)f2bf(acc[2] * inv) | ((unsigned)f2bf(acc[3] * inv) << 16);
            o.z = (unsigned)f2bf(acc[4] * inv) | ((unsigned)f2bf(acc[5] * inv) << 16);
            o.w = (unsigned)f2bf(acc[6] * inv) | ((unsigned)f2bf(acc[7] * inv) << 16);
            *(uint4*)(outb + (size_t)wave * ostride + ooff + q * 8) = o;
        } else {
            float4* op = (float4*)(outf + (size_t)wave * 64 + q * 8);
            float4 o0 = op[0], o1 = op[1];
            o0.x += acc[0] * inv; o0.y += acc[1] * inv;
            o0.z += acc[2] * inv; o0.w += acc[3] * inv;
            o1.x += acc[4] * inv; o1.y += acc[5] * inv;
            o1.z += acc[6] * inv; o1.w += acc[7] * inv;
            op[0] = o0; op[1] = o1;
        }
    }
}

// ---------------- MFMA conv: B in registers, multi-tile per wave, A prefetch -------
template<bool IS1>
__global__ __launch_bounds__(256) void conv_mfma_kernel(
    const unsigned short* __restrict__ A, const unsigned short* __restrict__ BT,
    const float* __restrict__ bias,
    unsigned short* __restrict__ outb, float* __restrict__ outf,
    float* __restrict__ sums, float* __restrict__ sumsq)
{
    __shared__ float red_s[4][128];
    __shared__ float red_q[4][128];
    int tid = threadIdx.x;
    int wid = tid >> 6, lane = tid & 63;
    int m = lane & 15, ko = lane >> 4;
    int gw = blockIdx.x * 4 + wid;
    int jh = gw & 1;                       // j-half this wave owns
    int tstride = (gridDim.x * 4) >> 1;
    const int tiles = NN / 16;             // 3125, exact
    // preload B fragments for this j-half (16 x bf16x8 = 64 VGPRs)
    bf16x8 b[4][4];
    const unsigned short* bbase = BT + (size_t)(jh * 64 + m) * 128 + ko * 8;
#pragma unroll
    for (int jg = 0; jg < 4; jg++)
#pragma unroll
        for (int ks = 0; ks < 4; ks++)
            b[jg][ks] = *(const bf16x8*)(bbase + jg * 16 * 128 + ks * 32);
    float bj[4];
#pragma unroll
    for (int jg = 0; jg < 4; jg++)
        bj[jg] = IS1 ? bias[jh * 64 + jg * 16 + m] : (jh ? bias[jg * 16 + m] : 0.f);
    float s_sum[4] = {0.f, 0.f, 0.f, 0.f}, s_sq[4] = {0.f, 0.f, 0.f, 0.f};
    int tile = gw >> 1;
    bf16x8 a[4];
    if (tile < tiles) {
        const unsigned short* arow = A + (size_t)(tile * 16 + m) * 128 + ko * 8;
#pragma unroll
        for (int ks = 0; ks < 4; ks++) a[ks] = *(const bf16x8*)(arow + ks * 32);
    }
    while (tile < tiles) {
        int nxt = tile + tstride;
        bf16x8 an[4];
        if (nxt < tiles) {
            const unsigned short* arow = A + (size_t)(nxt * 16 + m) * 128 + ko * 8;
#pragma unroll
            for (int ks = 0; ks < 4; ks++) an[ks] = *(const bf16x8*)(arow + ks * 32);
        }
        int n0 = tile * 16;
#pragma unroll
        for (int jg = 0; jg < 4; jg++) {
            f32x4 acc = {0.f, 0.f, 0.f, 0.f};
#pragma unroll
            for (int ks = 0; ks < 4; ks++)
                acc = __builtin_amdgcn_mfma_f32_16x16x32_bf16(a[ks], b[jg][ks], acc, 0, 0, 0);
            int j = jh * 64 + jg * 16 + m;
#pragma unroll
            for (int r = 0; r < 4; r++) {
                int n = n0 + ko * 4 + r;
                float v = acc[r];
                if (IS1) {
                    v += bj[jg];
                    outb[(size_t)n * 128 + j] = f2bf(v);
                    s_sum[jg] += v;
                    s_sq[jg] += v * v;
                } else {
                    if (jh == 0) outb[(size_t)n * 64 + j] = f2bf(v);
                    else         outf[(size_t)n * 64 + (j - 64)] = v + bj[jg];
                }
            }
        }
#pragma unroll
        for (int ks = 0; ks < 4; ks++) a[ks] = an[ks];
        tile = nxt;
    }
    if (IS1) {
        for (int i = tid; i < 512; i += 256) {
            ((float*)red_s)[i] = 0.f;
            ((float*)red_q)[i] = 0.f;
        }
        __syncthreads();
#pragma unroll
        for (int jg = 0; jg < 4; jg++) {
            float v = s_sum[jg];
            v += __shfl_xor(v, 16, 64);
            v += __shfl_xor(v, 32, 64);
            float w = s_sq[jg];
            w += __shfl_xor(w, 16, 64);
            w += __shfl_xor(w, 32, 64);
            if (lane < 16) {
                red_s[wid][jh * 64 + jg * 16 + lane] = v;
                red_q[wid][jh * 64 + jg * 16 + lane] = w;
            }
        }
        __syncthreads();
        if (tid < 128) {
            float v = red_s[0][tid] + red_s[1][tid] + red_s[2][tid] + red_s[3][tid];
            atomicAdd(&sums[tid], v);
        } else {
            int j = tid - 128;
            float v = red_q[0][j] + red_q[1][j] + red_q[2][j] + red_q[3][j];
            atomicAdd(&sumsq[j], v);
        }
    }
}

// ---------------- BN stats -> scale/shift ----------------
__global__ void bnstat_kernel(const float* __restrict__ sums, const float* __restrict__ sumsq,
                              const float* __restrict__ gamma, const float* __restrict__ beta,
                              float* __restrict__ scale, float* __restrict__ shift) {
    int c = threadIdx.x;
    if (c < HID) {
        float inv_n = 1.0f / (float)NN;
        float mu = sums[c] * inv_n;
        float var = sumsq[c] * inv_n - mu * mu;
        float s = gamma[c] * rsqrtf(var + 1e-5f);
        scale[c] = s;
        shift[c] = beta[c] - mu * s;
    }
}

// ---------------- bn+relu apply: h = relu(bn(hpreb)) bf16 -> A1 ----------------
__global__ void bnapply_kernel(const unsigned short* __restrict__ hpreb,
                               const float* __restrict__ scale, const float* __restrict__ shift,
                               unsigned short* __restrict__ A1) {
    int idx = blockIdx.x * 256 + threadIdx.x;   // NN*16 octet slots
    if (idx >= NN * 16) return;
    int q = idx & 15;
    int j0 = q * 8;
    uint4 v = ((const uint4*)hpreb)[idx];
    float f[8];
    f[0] = bflo(v.x); f[1] = bfhi(v.x);
    f[2] = bflo(v.y); f[3] = bfhi(v.y);
    f[4] = bflo(v.z); f[5] = bfhi(v.z);
    f[6] = bflo(v.w); f[7] = bfhi(v.w);
#pragma unroll
    for (int t = 0; t < 8; t++) {
        float h = f[t] * scale[j0 + t] + shift[j0 + t];
        f[t] = h > 0.f ? h : 0.f;
    }
    uint4 o;
    o.x = (unsigned)f2bf(f[0]) | ((unsigned)f2bf(f[1]) << 16);
    o.y = (unsigned)f2bf(f[2]) | ((unsigned)f2bf(f[3]) << 16);
    o.z = (unsigned)f2bf(f[4]) | ((unsigned)f2bf(f[5]) << 16);
    o.w = (unsigned)f2bf(f[6]) | ((unsigned)f2bf(f[7]) << 16);
    ((uint4*)A1)[idx] = o;
}

extern "C" void kernel_launch(void* const* d_in, const int* in_sizes, int n_in,
                              void* d_out, int out_size, void* d_ws, size_t ws_size,
                              hipStream_t stream) {
    const float* x     = (const float*)d_in[0];
    const int*   ei    = (const int*)d_in[1];
    const float* W1l   = (const float*)d_in[2];
    const float* b1    = (const float*)d_in[3];
    const float* W1r   = (const float*)d_in[4];
    const float* gamma = (const float*)d_in[5];
    const float* beta  = (const float*)d_in[6];
    const float* W2l   = (const float*)d_in[7];
    const float* b2    = (const float*)d_in[8];
    const float* W2r   = (const float*)d_in[9];
    float* out = (float*)d_out;

    // workspace layout (~35.5 MB; <= proven ~38.6 MB budget)
    char* wsb = (char*)d_ws;
    int*   bcnt   = (int*)wsb;                                  // 256 (memset with sums)
    float* sums   = (float*)(bcnt + 256);                       // 128
    float* sumsq  = sums + 128;                                 // 128
    float* scale  = sums + 256;                                 // 128
    float* shift  = sums + 384;                                 // 128
    int*   gstart = (int*)(sums + 512);                         // 256 (201 used)
    int*   gcur   = gstart + 256;                               // 256
    int*   startp = gcur + 256;                                 // NN
    int*   perm   = startp + NN;                                // NE
    int2*  pairs  = (int2*)(perm + NE);                         // NE int2
    unsigned short* A1    = (unsigned short*)(pairs + NE);      // NN*128 bf16
    unsigned short* hpreb = A1 + (size_t)NN * 128;              // NN*128 bf16; reused as pb
    unsigned short* BT1   = hpreb + (size_t)NN * 128;           // 128*128 bf16
    unsigned short* BT2   = BT1 + 128 * 128;                    // 128*128 bf16

    const int* srcp = ei;
    const int* dstp = ei + NE;

    // zero bcnt + sums + sumsq in one shot (contiguous)
    hipMemsetAsync(bcnt, 0, sizeof(int) * 512, stream);

    const int GB = (NN * 64 + 255) / 256;   // one wave per node
    const int CB = 512;                     // conv grid

    prep_kernel<<<XB + 64 + HB, 256, 0, stream>>>(x, A1, W1l, W1r, W2l, W2r,
                                                  BT1, BT2, dstp, bcnt);
    scanB_kernel<<<1, 256, 0, stream>>>(bcnt, gstart, gcur);
    binA_kernel<<<HB, 256, 0, stream>>>(srcp, dstp, gcur, pairs);
    binB_kernel<<<NBK, 256, 0, stream>>>(pairs, gstart, startp, perm);

    // agg1: gather A1 x-half (cols 64:128) -> bf16 mean into A1 cols 0:64
    agg_gather_b<0><<<GB, 256, 0, stream>>>(A1, 128, 64, startp, perm, A1, 128, 0, nullptr);
    // conv1: hpre = A1 @ [W1l;W1r] + b1 ; bf16 store + fp32 BN stats
    conv_mfma_kernel<true><<<CB, 256, 0, stream>>>(A1, BT1, b1, hpreb, nullptr, sums, sumsq);
    bnstat_kernel<<<1, 128, 0, stream>>>(sums, sumsq, gamma, beta, scale, shift);
    // h = relu(bn(hpreb)) -> A1
    bnapply_kernel<<<XB, 256, 0, stream>>>(hpreb, scale, shift, A1);
    // conv2: [p | self] = A1 @ [W2l|W2r] ; p bf16 -> hpreb(=pb), self+b2 -> out
    conv_mfma_kernel<false><<<CB, 256, 0, stream>>>(A1, BT2, b2, hpreb, out, nullptr, nullptr);
    // agg2: gather pb rows -> out += mean
    agg_gather_b<1><<<GB, 256, 0, stream>>>(hpreb, 64, 0, startp, perm, nullptr, 0, 0, out);
}